// Round 7
// baseline (284.868 us; speedup 1.0000x reference)
//
#include <hip/hip_runtime.h>
#include <hip/hip_bf16.h>
#include <math.h>

#define DIM 768
#define NTOK 4096   // B*N = 2*2048
#define SEQ 2048
#define HEADS 12
#define HD 64

using bf16x8 = __attribute__((ext_vector_type(8))) __bf16;
using bf16x4 = __attribute__((ext_vector_type(4))) __bf16;
using short4v = __attribute__((ext_vector_type(4))) short;
using f32x4  = __attribute__((ext_vector_type(4))) float;
typedef unsigned short u16;

#define KEXPF 0.18033688011112042f  // log2(e)/8

__device__ inline u16 f2bf(float f) {
  union { float f; unsigned u; } v; v.f = f;
  unsigned r = v.u + 0x7fffu + ((v.u >> 16) & 1u);  // RNE
  return (u16)(r >> 16);
}

// packed f32x2 -> bf16x2 (v_cvt_pk_bf16_f32)
__device__ inline void pk2bf(float a, float b, u16* o0, u16* o1) {
  union { __hip_bfloat162 h; u16 u[2]; } cv;
  cv.h = __float22bfloat162_rn(make_float2(a, b));
  *o0 = cv.u[0];
  *o1 = cv.u[1];
}

// packed f32x2 -> one u32 of 2 bf16 (lo = a, hi = b)
__device__ inline unsigned pku32(float a, float b) {
  union { __hip_bfloat162 h; unsigned u; } cv;
  cv.h = __float22bfloat162_rn(make_float2(a, b));
  return cv.u;
}

// GELU, sigmoid form: x*sigmoid(1.5957691x + 0.0713548x^3); |err| < ~3e-3.
__device__ inline float gelu_t(float x) {
  float z = x * (1.5957691216f + 0.0713548162f * x * x);
  return x / (1.0f + __expf(-z));
}

// async global->LDS DMA, 16 B per lane; LDS dest = wave-uniform base + lane*16
__device__ inline void gl_lds16(const u16* g, u16* l) {
  __builtin_amdgcn_global_load_lds(
      (const __attribute__((address_space(1))) unsigned int*)g,
      (__attribute__((address_space(3))) unsigned int*)l, 16, 0, 0);
}

// ---------------- LayerNorm: fp32 in -> bf16 out ----------------
__global__ __launch_bounds__(256) void ln_kernel(const float* __restrict__ x,
                                                 const float* __restrict__ w,
                                                 const float* __restrict__ b,
                                                 u16* __restrict__ y) {
  int row = blockIdx.x;
  int t = threadIdx.x;
  const float* xr = x + (size_t)row * DIM;
  float v0 = xr[t], v1 = xr[t + 256], v2 = xr[t + 512];
  float s = v0 + v1 + v2;
  float q = v0 * v0 + v1 * v1 + v2 * v2;
  for (int o = 32; o > 0; o >>= 1) {
    s += __shfl_down(s, o, 64);
    q += __shfl_down(q, o, 64);
  }
  __shared__ float ws_[4], wq_[4], mb[2];
  int wid = t >> 6;
  if ((t & 63) == 0) { ws_[wid] = s; wq_[wid] = q; }
  __syncthreads();
  if (t == 0) {
    float S = ws_[0] + ws_[1] + ws_[2] + ws_[3];
    float Q = wq_[0] + wq_[1] + wq_[2] + wq_[3];
    float mean = S * (1.0f / DIM);
    float var = Q * (1.0f / DIM) - mean * mean;
    mb[0] = mean;
    mb[1] = rsqrtf(var + 1e-5f);
  }
  __syncthreads();
  float mean = mb[0], rstd = mb[1];
  u16* yr = y + (size_t)row * DIM;
  yr[t]       = f2bf((v0 - mean) * rstd * w[t]       + b[t]);
  yr[t + 256] = f2bf((v1 - mean) * rstd * w[t + 256] + b[t + 256]);
  yr[t + 512] = f2bf((v2 - mean) * rstd * w[t + 512] + b[t + 512]);
}

// -------- fused split-K reduce + residual + bias -> x2 (fp32) + LN -> h (bf16)
__global__ __launch_bounds__(256) void redln_kernel(
    const float* __restrict__ P0, const float* __restrict__ P1,
    const float* __restrict__ bias, const float* __restrict__ res,
    float* __restrict__ x2, const float* __restrict__ lnw,
    const float* __restrict__ lnb, u16* __restrict__ y) {
  int row = blockIdx.x;
  int t = threadIdx.x;
  size_t off = (size_t)row * DIM;
  float v[3];
#pragma unroll
  for (int k = 0; k < 3; ++k) {
    int c = t + k * 256;
    v[k] = P0[off + c] + P1[off + c] + bias[c] + res[off + c];
    x2[off + c] = v[k];
  }
  float s = v[0] + v[1] + v[2];
  float q = v[0] * v[0] + v[1] * v[1] + v[2] * v[2];
  for (int o = 32; o > 0; o >>= 1) {
    s += __shfl_down(s, o, 64);
    q += __shfl_down(q, o, 64);
  }
  __shared__ float ws_[4], wq_[4], mb[2];
  int wid = t >> 6;
  if ((t & 63) == 0) { ws_[wid] = s; wq_[wid] = q; }
  __syncthreads();
  if (t == 0) {
    float S = ws_[0] + ws_[1] + ws_[2] + ws_[3];
    float Q = wq_[0] + wq_[1] + wq_[2] + wq_[3];
    float mean = S * (1.0f / DIM);
    float var = Q * (1.0f / DIM) - mean * mean;
    mb[0] = mean;
    mb[1] = rsqrtf(var + 1e-5f);
  }
  __syncthreads();
  float mean = mb[0], rstd = mb[1];
#pragma unroll
  for (int k = 0; k < 3; ++k) {
    int c = t + k * 256;
    y[off + c] = f2bf((v[k] - mean) * rstd * lnw[c] + lnb[c]);
  }
}

// ---------------- all 4 weight converts in one launch (dims compile-time) ----
__global__ __launch_bounds__(256) void wcvt_all(
    const float* __restrict__ W0, const float* __restrict__ W1,
    const float* __restrict__ W2, const float* __restrict__ W3,
    u16* __restrict__ T0, u16* __restrict__ T1,
    u16* __restrict__ T2, u16* __restrict__ T3) {
  int id = blockIdx.x;
  const float* W; u16* Wt; int K, N, local;
  if (id < 1728)      { W = W0; Wt = T0; K = 768;  N = 2304; local = id; }
  else if (id < 2304) { W = W1; Wt = T1; K = 768;  N = 768;  local = id - 1728; }
  else if (id < 4608) { W = W2; Wt = T2; K = 768;  N = 3072; local = id - 2304; }
  else                { W = W3; Wt = T3; K = 3072; N = 768;  local = id - 4608; }
  int ntiles = N / 32;
  int n0 = (local % ntiles) * 32, k0 = (local / ntiles) * 32;
  __shared__ float tile[32][33];
  int tid = threadIdx.x;
  int c = tid & 31, r8 = tid >> 5;
#pragma unroll
  for (int p = 0; p < 4; ++p) {
    int k = r8 + p * 8;
    tile[k][c] = W[(size_t)(k0 + k) * N + n0 + c];
  }
  __syncthreads();
#pragma unroll
  for (int p = 0; p < 4; ++p) {
    int n = r8 + p * 8;
    Wt[(size_t)(n0 + n) * K + k0 + c] = f2bf(tile[c][n]);
  }
}

// ---------------- V transpose: qkvB V-slice -> vT[b][v][j] ----------------
__global__ __launch_bounds__(256) void vtr_kernel(const u16* __restrict__ qkvB,
                                                  u16* __restrict__ vT) {
  __shared__ u16 tile[32][33];
  int v0 = blockIdx.x * 32, j0 = blockIdx.y * 32, b = blockIdx.z;
  int tid = threadIdx.x;
  int c = tid & 31, r8 = tid >> 5;
#pragma unroll
  for (int p = 0; p < 4; ++p) {
    int r = r8 + p * 8;
    tile[r][c] = qkvB[((size_t)(b * SEQ + j0 + r)) * 2304 + 1536 + v0 + c];
  }
  __syncthreads();
#pragma unroll
  for (int p = 0; p < 4; ++p) {
    int r = r8 + p * 8;
    vT[((size_t)(b * 768 + v0 + r)) * SEQ + j0 + c] = tile[c][r];
  }
}

// ---------------- bf16 MFMA GEMM (full-K): Cb = act(A * Bt^T + bias) --------
// R7: quad-buffer [2 halves][2 sub-steps] of BK=32 — LDS stays 32 KB (the R5
// 64 KB occupancy regression is avoided) but the barrier cadence halves vs R6:
// one {A-barrier, 8-DMA stage, vmcnt(8), B-barrier} per 64-k (2 sub-steps, 32
// MFMAs), matching the splitk kernels' cadence. vmcnt(8) retires exactly the
// NEXT pair's 8 loads (issue-order), giving a full 64-k compute window of
// latency hiding. Swizzle identical to R6 per sub-step.
__global__ __launch_bounds__(256) void bgemm_kernel(
    const u16* __restrict__ A, const u16* __restrict__ Bt,
    const float* __restrict__ bias, u16* __restrict__ Cb,
    int M, int N, int K, int act, int scaleq) {
  __shared__ __align__(16) u16 Asl[2][2][128 * 32];  // [half][sub]
  __shared__ __align__(16) u16 Bsl[2][2][128 * 32];
  int nwg = gridDim.x * gridDim.y;
  int bid = blockIdx.y * gridDim.x + blockIdx.x;
  int swz = (bid & 7) * (nwg >> 3) + (bid >> 3);
  int bx = swz % gridDim.x, by = swz / gridDim.x;
  int tid = threadIdx.x;
  int lane = tid & 63, wave = tid >> 6;
  int wm = wave >> 1, wn = wave & 1;
  int bm = by * 128, bn = bx * 128;
  int l15 = lane & 15, quad = lane >> 4;
  int srow4 = lane >> 2;                        // 0..15: row within 16-row chunk
  int gux = (lane & 3) ^ ((srow4 + (srow4 >> 2)) & 3);  // swizzled global unit

  f32x4 acc[4][4] = {};
  const u16* Ap = A + (size_t)(bm + wave * 16 + srow4) * K + gux * 8;
  const u16* Bp = Bt + (size_t)(bn + wave * 16 + srow4) * K + gux * 8;
  int fx = (l15 + (l15 >> 2)) & 3;              // f(read row)
  int nit = K >> 6;                              // iterations of 64-k

  auto STAGE1 = [&](int k0, int half, int sub) {
#pragma unroll
    for (int p = 0; p < 2; ++p)
      gl_lds16(Ap + (size_t)(p * 64) * K + k0, &Asl[half][sub][(wave * 16 + p * 64) * 32]);
#pragma unroll
    for (int p = 0; p < 2; ++p)
      gl_lds16(Bp + (size_t)(p * 64) * K + k0, &Bsl[half][sub][(wave * 16 + p * 64) * 32]);
  };

  STAGE1(0, 0, 0);  STAGE1(32, 0, 1);           // pair 0
  if (nit > 1) { STAGE1(64, 1, 0); STAGE1(96, 1, 1); }  // pair 1
  asm volatile("s_waitcnt vmcnt(8)" ::: "memory");      // pair 0 complete
  __builtin_amdgcn_s_barrier();

  for (int it = 0; it < nit; ++it) {
    int half = it & 1;
#pragma unroll
    for (int sub = 0; sub < 2; ++sub) {
      bf16x8 af[4], bfr[4];
#pragma unroll
      for (int i = 0; i < 4; ++i) {
        af[i]  = *(const bf16x8*)&Asl[half][sub][(wm * 64 + i * 16 + l15) * 32 + (quad ^ fx) * 8];
        bfr[i] = *(const bf16x8*)&Bsl[half][sub][(wn * 64 + i * 16 + l15) * 32 + (quad ^ fx) * 8];
      }
#pragma unroll
      for (int i = 0; i < 4; ++i)
#pragma unroll
        for (int j = 0; j < 4; ++j)
          acc[i][j] = __builtin_amdgcn_mfma_f32_16x16x32_bf16(af[i], bfr[j], acc[i][j], 0, 0, 0);
    }
    if (it == nit - 1) break;
    __builtin_amdgcn_sched_barrier(0);
    __builtin_amdgcn_s_barrier();        // A: all reads of half done
    __builtin_amdgcn_sched_barrier(0);
    if (it + 2 < nit) {
      int k0 = (it + 2) << 6;
      STAGE1(k0, half, 0);  STAGE1(k0 + 32, half, 1);
      asm volatile("s_waitcnt vmcnt(8)" ::: "memory");  // retire pair it+1
    } else {
      asm volatile("s_waitcnt vmcnt(0)" ::: "memory");
    }
    __builtin_amdgcn_sched_barrier(0);
    __builtin_amdgcn_s_barrier();        // B: pair it+1 visible
    __builtin_amdgcn_sched_barrier(0);
  }

#pragma unroll
  for (int i = 0; i < 4; ++i) {
#pragma unroll
    for (int j = 0; j < 4; ++j) {
      int n = bn + wn * 64 + j * 16 + l15;
      float bv = bias[n];
      float cs = (scaleq && n < 768) ? KEXPF : 1.0f;
      float val[4];
#pragma unroll
      for (int r = 0; r < 4; ++r) {
        float v = (acc[i][j][r] + bv) * cs;
        val[r] = act ? gelu_t(v) : v;
      }
      u16 c0, c1, c2, c3;
      pk2bf(val[0], val[1], &c0, &c1);
      pk2bf(val[2], val[3], &c2, &c3);
      size_t mbase = (size_t)(bm + wm * 64 + i * 16 + quad * 4) * N + n;
      Cb[mbase]         = c0;
      Cb[mbase + N]     = c1;
      Cb[mbase + 2 * N] = c2;
      Cb[mbase + 3 * N] = c3;
    }
  }
}

// ---------------- bf16 MFMA GEMM, split-K x2, 128x64 tile, BK=64 ------------
// R5 structure kept: counted-vmcnt double-buffer, 48 KB LDS (3 blocks/CU).
__global__ __launch_bounds__(256) void bgemm_splitk(
    const u16* __restrict__ A, const u16* __restrict__ Bt,
    float* __restrict__ P0, float* __restrict__ P1,
    int M, int N, int K) {
  __shared__ __align__(16) u16 Asl[2][128 * 64];
  __shared__ __align__(16) u16 Bsl[2][64 * 64];
  int nwg = gridDim.x * gridDim.y;
  int bid = blockIdx.y * gridDim.x + blockIdx.x;
  int swz = (bid & 7) * (nwg >> 3) + (bid >> 3);
  int bx = swz % gridDim.x, by = swz / gridDim.x;
  int tid = threadIdx.x;
  int lane = tid & 63, wave = tid >> 6;
  int wm = wave >> 1, wn = wave & 1;
  int bm = by * 128, bn = bx * 64;
  int l15 = lane & 15, quad = lane >> 4;
  int sm8 = tid >> 3;
  int kgx = (tid & 7) ^ (sm8 & 7);
  int half = K >> 1;
  int kbeg = blockIdx.z * half;

  f32x4 acc[4][2] = {};
  const u16* Ap = A + (size_t)(bm + sm8) * K + kbeg + kgx * 8;
  const u16* Bp = Bt + (size_t)(bn + sm8) * K + kbeg + kgx * 8;
  int xr = l15 & 7;
  int nk = half >> 6;

  auto STAGE = [&](int k0, int sel) {
#pragma unroll
    for (int p = 0; p < 4; ++p)
      gl_lds16(Ap + (size_t)(p * 32) * K + k0, &Asl[sel][(wave * 8 + p * 32) * 64]);
#pragma unroll
    for (int p = 0; p < 2; ++p)
      gl_lds16(Bp + (size_t)(p * 32) * K + k0, &Bsl[sel][(wave * 8 + p * 32) * 64]);
  };

  STAGE(0, 0);
  if (nk > 1) STAGE(64, 1);
  asm volatile("s_waitcnt vmcnt(6)" ::: "memory");
  __builtin_amdgcn_s_barrier();

  for (int t = 0; t < nk; ++t) {
    int sel = t & 1;
#pragma unroll
    for (int ks = 0; ks < 2; ++ks) {
      int pu = ((ks << 2) + quad) ^ xr;
      bf16x8 af[4], bfr[2];
#pragma unroll
      for (int i = 0; i < 4; ++i)
        af[i] = *(const bf16x8*)&Asl[sel][(wm * 64 + i * 16 + l15) * 64 + pu * 8];
#pragma unroll
      for (int j = 0; j < 2; ++j)
        bfr[j] = *(const bf16x8*)&Bsl[sel][(wn * 32 + j * 16 + l15) * 64 + pu * 8];
#pragma unroll
      for (int i = 0; i < 4; ++i)
#pragma unroll
        for (int j = 0; j < 2; ++j)
          acc[i][j] = __builtin_amdgcn_mfma_f32_16x16x32_bf16(af[i], bfr[j], acc[i][j], 0, 0, 0);
    }
    if (t == nk - 1) break;
    __builtin_amdgcn_sched_barrier(0);
    __builtin_amdgcn_s_barrier();        // A
    __builtin_amdgcn_sched_barrier(0);
    if (t + 2 < nk) {
      STAGE((t + 2) << 6, sel);
      asm volatile("s_waitcnt vmcnt(6)" ::: "memory");
    } else {
      asm volatile("s_waitcnt vmcnt(0)" ::: "memory");
    }
    __builtin_amdgcn_sched_barrier(0);
    __builtin_amdgcn_s_barrier();        // B
    __builtin_amdgcn_sched_barrier(0);
  }

  float* P = blockIdx.z ? P1 : P0;
#pragma unroll
  for (int i = 0; i < 4; ++i) {
#pragma unroll
    for (int j = 0; j < 2; ++j) {
      int n = bn + wn * 32 + j * 16 + l15;
#pragma unroll
      for (int r = 0; r < 4; ++r) {
        int m = bm + wm * 64 + i * 16 + quad * 4 + r;
        P[(size_t)m * N + n] = acc[i][j][r];
      }
    }
  }
}

// ---------------- split-K reduce: O = P0 + P1 + bias + res ------------------
__global__ __launch_bounds__(256) void red_kernel(
    const float* P0, const float* __restrict__ P1,
    const float* __restrict__ bias, const float* __restrict__ res,
    float* O, int Ncols) {
  int i = blockIdx.x * 256 + threadIdx.x;
  float4 a = ((const float4*)P0)[i];
  float4 b = ((const float4*)P1)[i];
  float4 r = ((const float4*)res)[i];
  int col = (i * 4) % Ncols;
  float4 bi = *(const float4*)&bias[col];
  float4 o;
  o.x = a.x + b.x + r.x + bi.x;
  o.y = a.y + b.y + r.y + bi.y;
  o.z = a.z + b.z + r.z + bi.z;
  o.w = a.w + b.w + r.w + bi.w;
  ((float4*)O)[i] = o;
}

// ---------------- 4-wave MFMA flash attention, j-partitioned ----------------
// R4 structure (counted-vmcnt pipeline, ones-MFMA lsum, pre-scaled Q)
// + R5 XCD-aware bijective block swizzle. Unchanged this round.
#define LDP 68
__global__ __launch_bounds__(256, 3) void attn_kernel(const u16* __restrict__ qkv,
                                                      const u16* __restrict__ vT,
                                                      u16* __restrict__ out) {
  __shared__ __align__(16) char arena[40960];
  u16* Qsp = (u16*)arena;                 // 64x64 u16 (8 KB)
  u16* Ksp = (u16*)(arena + 8192);        // [2][64x64] u16 (16 KB)
  u16* Vsp = (u16*)(arena + 24576);       // [2][64x64] u16 (16 KB)

  int nwg = gridDim.x * gridDim.y * gridDim.z;
  int bid = (blockIdx.z * gridDim.y + blockIdx.y) * gridDim.x + blockIdx.x;
  int swz = (bid & 7) * (nwg >> 3) + (bid >> 3);
  int bx = swz % gridDim.x;
  int rem = swz / gridDim.x;
  int h = rem % gridDim.y, b = rem / gridDim.y;

  int tid = threadIdx.x;
  int lane = tid & 63, wave = tid >> 6;
  int l15 = lane & 15, quad = lane >> 4;
  int qt = bx * 64;
  size_t base = (size_t)b * SEQ;
  int srow = lane >> 3;                 // 0..7 within an 8-row DMA chunk
  int sux = (lane & 7) ^ (srow & 7);    // XOR-swizzled global 16B col-unit
  int r0 = wave * 16;                   // this wave's staging row base
  const u16* qbase = qkv + (base + qt) * 2304 + h * HD;
  const u16* kbase = qkv + base * 2304 + 768 + h * HD;
  const u16* vbase = vT + ((size_t)(b * HEADS + h) * HD) * SEQ;

  // stage Q + K/V tile 0 (wave w covers rows r0..r0+15 = two 8-row chunks)
  gl_lds16(qbase + (size_t)(r0 + srow) * 2304 + sux * 8, Qsp + r0 * 64);
  gl_lds16(qbase + (size_t)(r0 + 8 + srow) * 2304 + sux * 8, Qsp + (r0 + 8) * 64);
  gl_lds16(kbase + (size_t)(r0 + srow) * 2304 + sux * 8, Ksp + r0 * 64);
  gl_lds16(kbase + (size_t)(r0 + 8 + srow) * 2304 + sux * 8, Ksp + (r0 + 8) * 64);
  gl_lds16(vbase + (size_t)(r0 + srow) * SEQ + sux * 8, Vsp + r0 * 64);
  gl_lds16(vbase + (size_t)(r0 + 8 + srow) * SEQ + sux * 8, Vsp + (r0 + 8) * 64);
  __syncthreads();   // full drain: tile-0 data + Q visible

  int xr = l15 & 7;
  // Q-frags: q-group g rows g*16+l15, k-step s (32 k each)
  bf16x8 qf[4][2];
#pragma unroll
  for (int g = 0; g < 4; ++g)
#pragma unroll
    for (int s = 0; s < 2; ++s)
      qf[g][s] = *(const bf16x8*)&Qsp[(g * 16 + l15) * 64 + ((s * 4 + quad) ^ xr) * 8];

  // prefetch tile 1 into buf 1 (in flight across tile 0's compute)
  gl_lds16(kbase + (size_t)(64 + r0 + srow) * 2304 + sux * 8, Ksp + 4096 + r0 * 64);
  gl_lds16(kbase + (size_t)(64 + r0 + 8 + srow) * 2304 + sux * 8, Ksp + 4096 + (r0 + 8) * 64);
  gl_lds16(vbase + (size_t)(r0 + srow) * SEQ + 64 + sux * 8, Vsp + 4096 + r0 * 64);
  gl_lds16(vbase + (size_t)(r0 + 8 + srow) * SEQ + 64 + sux * 8, Vsp + 4096 + (r0 + 8) * 64);

  // tile-invariant LDS element offsets
  int koff0 = (wave * 16 + l15) * 64 + ((quad ^ xr)) * 8;
  int koff1 = (wave * 16 + l15) * 64 + (((4 + quad) ^ xr)) * 8;
  int voff[4];
#pragma unroll
  for (int dg = 0; dg < 4; ++dg)
    voff[dg] = (dg * 16 + l15) * 64 + (((2 * wave + (quad >> 1)) ^ xr)) * 8 + (quad & 1) * 4;

  f32x4 oT[4][4] = {};   // [dg][g] : O^T tiles (d rows, q cols), j-partial
  f32x4 oT1[4] = {};     // [g] : ones-row accumulators (stripe row-sums of P)
  const short4v ONES = {(short)0x3F80, (short)0x3F80, (short)0x3F80, (short)0x3F80};
  int buf = 0;

  for (int t = 0; t < 32; ++t) {
    const u16* Kb = Ksp + buf * 4096;
    const u16* Vb = Vsp + buf * 4096;

    // QK^T: S^T[j-stripe 16][q 64] ; lane: j=16w+quad*4+r, q=16g+l15
    f32x4 sT[4] = {};
    __builtin_amdgcn_s_setprio(1);
    {
      bf16x8 ak = *(const bf16x8*)&Kb[koff0];
#pragma unroll
      for (int g = 0; g < 4; ++g)
        sT[g] = __builtin_amdgcn_mfma_f32_16x16x32_bf16(ak, qf[g][0], sT[g], 0, 0, 0);
      bf16x8 ak1 = *(const bf16x8*)&Kb[koff1];
#pragma unroll
      for (int g = 0; g < 4; ++g)
        sT[g] = __builtin_amdgcn_mfma_f32_16x16x32_bf16(ak1, qf[g][1], sT[g], 0, 0, 0);
    }
    __builtin_amdgcn_s_setprio(0);

    // softmax (max-free, Q pre-scaled): p = 2^s ; pack -> x16 B-frags
    short4v pb[4];
#pragma unroll
    for (int g = 0; g < 4; ++g) {
      float p0 = __builtin_amdgcn_exp2f(sT[g][0]);
      float p1 = __builtin_amdgcn_exp2f(sT[g][1]);
      float p2 = __builtin_amdgcn_exp2f(sT[g][2]);
      float p3 = __builtin_amdgcn_exp2f(sT[g][3]);
      union { unsigned u[2]; short4v s; } cv;
      cv.u[0] = pku32(p0, p1);
      cv.u[1] = pku32(p2, p3);
      pb[g] = cv.s;
    }

    // PV: oT[dg][g] += V^T[d-block][stripe] * P^T[stripe][q-group]
    // + ones row: oT1[g] += 1s * P^T  (stripe row-sum -> l partials)
    short4v av[4];
#pragma unroll
    for (int dg = 0; dg < 4; ++dg)
      av[dg] = *(const short4v*)&Vb[voff[dg]];
    __builtin_amdgcn_s_setprio(1);
#pragma unroll
    for (int dg = 0; dg < 4; ++dg)
#pragma unroll
      for (int g = 0; g < 4; ++g)
        oT[dg][g] = __builtin_amdgcn_mfma_f32_16x16x16bf16_1k(av[dg], pb[g], oT[dg][g], 0, 0, 0);
#pragma unroll
    for (int g = 0; g < 4; ++g)
      oT1[g] = __builtin_amdgcn_mfma_f32_16x16x16bf16_1k(ONES, pb[g], oT1[g], 0, 0, 0);
    __builtin_amdgcn_s_setprio(0);

    __builtin_amdgcn_sched_barrier(0);
    __builtin_amdgcn_s_barrier();          // A: all reads of buf done
    __builtin_amdgcn_sched_barrier(0);
    if (t < 30) {  // prefetch tile t+2 into the buffer just freed
      size_t kt2 = (size_t)(t + 2) * 64;
      u16* Kd = Ksp + buf * 4096;
      u16* Vd = Vsp + buf * 4096;
      gl_lds16(kbase + (kt2 + r0 + srow) * 2304 + sux * 8, Kd + r0 * 64);
      gl_lds16(kbase + (kt2 + r0 + 8 + srow) * 2304 + sux * 8, Kd + (r0 + 8) * 64);
      gl_lds16(vbase + (size_t)(r0 + srow) * SEQ + kt2 + sux * 8, Vd + r0 * 64);
      gl_lds16(vbase + (size_t)(r0 + 8 + srow) * SEQ + kt2 + sux * 8, Vd + (r0 + 8) * 64);
      asm volatile("s_waitcnt vmcnt(4)" ::: "memory");  // retire t+1's 4 loads
    } else {
      asm volatile("s_waitcnt vmcnt(0)" ::: "memory");
    }
    __builtin_amdgcn_sched_barrier(0);
    __builtin_amdgcn_s_barrier();          // B: t+1 data visible to all waves
    __builtin_amdgcn_sched_barrier(0);
    buf ^= 1;
  }

  // ---- epilogue: cross-wave reduce of j-partial O^T + l, then write ----
  // (barriers A+B of t=31 guarantee all K/V reads done -> arena reusable)
  float* LDSw = (float*)arena;             // [4 waves][16 d][LDP] f32 (17408 B)
  float* lsd  = (float*)(arena + 17408);   // [4 waves][4 g][16] f32 (1 KB)
  if (lane < 16) {
#pragma unroll
    for (int g = 0; g < 4; ++g) lsd[wave * 64 + g * 16 + lane] = oT1[g][0];
  }
  float linv = 0.f;
#pragma unroll
  for (int dg = 0; dg < 4; ++dg) {
    // write phase: wave u writes its oT tiles for d-chunk dg
#pragma unroll
    for (int g = 0; g < 4; ++g)
#pragma unroll
      for (int r = 0; r < 4; ++r)
        LDSw[wave * (16 * LDP) + (quad * 4 + r) * LDP + g * 16 + l15] = oT[dg][g][r];
    __syncthreads();
    if (dg == 0) {
      float L = lsd[wave * 16 + l15] + lsd[64 + wave * 16 + l15] +
                lsd[128 + wave * 16 + l15] + lsd[192 + wave * 16 + l15];
      linv = 1.0f / L;
    }
    // sum phase: thread (wave,l15,quad) -> q = wave*16+l15, d = dg*16+quad*4+i
    float sv[4];
#pragma unroll
    for (int i = 0; i < 4; ++i) {
      int dloc = quad * 4 + i;
      float a = LDSw[dloc * LDP + wave * 16 + l15] +
                LDSw[1 * (16 * LDP) + dloc * LDP + wave * 16 + l15] +
                LDSw[2 * (16 * LDP) + dloc * LDP + wave * 16 + l15] +
                LDSw[3 * (16 * LDP) + dloc * LDP + wave * 16 + l15];
      sv[i] = a * linv;
    }
    size_t addr = (base + qt + wave * 16 + l15) * DIM + h * HD + dg * 16 + quad * 4;
    uint2 pk;
    pk.x = pku32(sv[0], sv[1]);
    pk.y = pku32(sv[2], sv[3]);
    *(uint2*)&out[addr] = pk;
    __syncthreads();  // before next chunk reuses LDSw
  }
}

extern "C" void kernel_launch(void* const* d_in, const int* in_sizes, int n_in,
                              void* d_out, int out_size, void* d_ws, size_t ws_size,
                              hipStream_t stream) {
  const float* x     = (const float*)d_in[0];
  const float* ln1w  = (const float*)d_in[1];
  const float* ln1b  = (const float*)d_in[2];
  const float* qkvw  = (const float*)d_in[3];
  const float* qkvbi = (const float*)d_in[4];
  const float* projw = (const float*)d_in[5];
  const float* projb = (const float*)d_in[6];
  const float* ln2w  = (const float*)d_in[7];
  const float* ln2b  = (const float*)d_in[8];
  const float* l1w   = (const float*)d_in[9];
  const float* l1b   = (const float*)d_in[10];
  const float* l2w   = (const float*)d_in[11];
  const float* l2b   = (const float*)d_in[12];
  float* out = (float*)d_out;

  char* w = (char*)d_ws;
  u16*   h     = (u16*)w;   w += (size_t)NTOK * DIM * 2;          // 6.3 MB
  u16*   qkvB  = (u16*)w;                                         // 18.9 MB (union)
  u16*   mid   = (u16*)w;   w += (size_t)NTOK * 3072 * 2;         // 25.2 MB union
  u16*   attnb = (u16*)w;   w += (size_t)NTOK * DIM * 2;          // 6.3 MB
  float* x2    = (float*)w; w += (size_t)NTOK * DIM * 4;          // 12.6 MB
  u16*   vTb   = (u16*)w;   w += (size_t)NTOK * DIM * 2;          // 6.3 MB
  u16*   qkvwt = (u16*)w;   w += (size_t)DIM * 2304 * 2;
  u16*   projwt= (u16*)w;   w += (size_t)DIM * DIM * 2;
  u16*   l1wt  = (u16*)w;   w += (size_t)DIM * 3072 * 2;
  u16*   l2wt  = (u16*)w;   w += (size_t)3072 * DIM * 2;
  float* Pbuf  = (float*)w; w += (size_t)NTOK * DIM * 4;          // 12.6 MB (split-K P1)

  wcvt_all<<<6912, 256, 0, stream>>>(qkvw, projw, l1w, l2w,
                                     qkvwt, projwt, l1wt, l2wt);

  ln_kernel<<<NTOK, 256, 0, stream>>>(x, ln1w, ln1b, h);
  bgemm_kernel<<<dim3(2304 / 128, NTOK / 128), 256, 0, stream>>>(
      h, qkvwt, qkvbi, qkvB, NTOK, 2304, DIM, 0, 1);
  vtr_kernel<<<dim3(768 / 32, SEQ / 32, 2), 256, 0, stream>>>(qkvB, vTb);
  attn_kernel<<<dim3(SEQ / 64, HEADS, 2), 256, 0, stream>>>(qkvB, vTb, attnb);

  // proj: split-K x2 -> x2 + Pbuf; fused reduce(+bias+x residual) + LN2
  bgemm_splitk<<<dim3(DIM / 64, NTOK / 128, 2), 256, 0, stream>>>(
      attnb, projwt, x2, Pbuf, NTOK, DIM, DIM);
  redln_kernel<<<NTOK, 256, 0, stream>>>(x2, Pbuf, projb, x, x2, ln2w, ln2b, h);

  bgemm_kernel<<<dim3(3072 / 128, NTOK / 128), 256, 0, stream>>>(
      h, l1wt, l1b, mid, NTOK, 3072, DIM, 1, 0);

  // lin2: split-K x2 -> out + Pbuf; reduce adds bias + x2 residual
  bgemm_splitk<<<dim3(DIM / 64, NTOK / 128, 2), 256, 0, stream>>>(
      mid, l2wt, out, Pbuf, NTOK, DIM, 3072);
  red_kernel<<<NTOK * DIM / 1024, 256, 0, stream>>>(out, Pbuf, l2b, x2, out, DIM);
}

// Round 8
// 269.841 us; speedup vs baseline: 1.0557x; 1.0557x over previous
//
#include <hip/hip_runtime.h>
#include <hip/hip_bf16.h>
#include <math.h>

#define DIM 768
#define NTOK 4096   // B*N = 2*2048
#define SEQ 2048
#define HEADS 12
#define HD 64

using bf16x8 = __attribute__((ext_vector_type(8))) __bf16;
using bf16x4 = __attribute__((ext_vector_type(4))) __bf16;
using short4v = __attribute__((ext_vector_type(4))) short;
using f32x4  = __attribute__((ext_vector_type(4))) float;
typedef unsigned short u16;

#define KEXPF 0.18033688011112042f  // log2(e)/8

__device__ inline u16 f2bf(float f) {
  union { float f; unsigned u; } v; v.f = f;
  unsigned r = v.u + 0x7fffu + ((v.u >> 16) & 1u);  // RNE
  return (u16)(r >> 16);
}

// packed f32x2 -> bf16x2 (v_cvt_pk_bf16_f32)
__device__ inline void pk2bf(float a, float b, u16* o0, u16* o1) {
  union { __hip_bfloat162 h; u16 u[2]; } cv;
  cv.h = __float22bfloat162_rn(make_float2(a, b));
  *o0 = cv.u[0];
  *o1 = cv.u[1];
}

// packed f32x2 -> one u32 of 2 bf16 (lo = a, hi = b)
__device__ inline unsigned pku32(float a, float b) {
  union { __hip_bfloat162 h; unsigned u; } cv;
  cv.h = __float22bfloat162_rn(make_float2(a, b));
  return cv.u;
}

// GELU, sigmoid form: x*sigmoid(1.5957691x + 0.0713548x^3); |err| < ~3e-3.
__device__ inline float gelu_t(float x) {
  float z = x * (1.5957691216f + 0.0713548162f * x * x);
  return x / (1.0f + __expf(-z));
}

// async global->LDS DMA, 16 B per lane; LDS dest = wave-uniform base + lane*16
__device__ inline void gl_lds16(const u16* g, u16* l) {
  __builtin_amdgcn_global_load_lds(
      (const __attribute__((address_space(1))) unsigned int*)g,
      (__attribute__((address_space(3))) unsigned int*)l, 16, 0, 0);
}

// ---------------- LayerNorm: fp32 in -> bf16 out ----------------
__global__ __launch_bounds__(256) void ln_kernel(const float* __restrict__ x,
                                                 const float* __restrict__ w,
                                                 const float* __restrict__ b,
                                                 u16* __restrict__ y) {
  int row = blockIdx.x;
  int t = threadIdx.x;
  const float* xr = x + (size_t)row * DIM;
  float v0 = xr[t], v1 = xr[t + 256], v2 = xr[t + 512];
  float s = v0 + v1 + v2;
  float q = v0 * v0 + v1 * v1 + v2 * v2;
  for (int o = 32; o > 0; o >>= 1) {
    s += __shfl_down(s, o, 64);
    q += __shfl_down(q, o, 64);
  }
  __shared__ float ws_[4], wq_[4], mb[2];
  int wid = t >> 6;
  if ((t & 63) == 0) { ws_[wid] = s; wq_[wid] = q; }
  __syncthreads();
  if (t == 0) {
    float S = ws_[0] + ws_[1] + ws_[2] + ws_[3];
    float Q = wq_[0] + wq_[1] + wq_[2] + wq_[3];
    float mean = S * (1.0f / DIM);
    float var = Q * (1.0f / DIM) - mean * mean;
    mb[0] = mean;
    mb[1] = rsqrtf(var + 1e-5f);
  }
  __syncthreads();
  float mean = mb[0], rstd = mb[1];
  u16* yr = y + (size_t)row * DIM;
  yr[t]       = f2bf((v0 - mean) * rstd * w[t]       + b[t]);
  yr[t + 256] = f2bf((v1 - mean) * rstd * w[t + 256] + b[t + 256]);
  yr[t + 512] = f2bf((v2 - mean) * rstd * w[t + 512] + b[t + 512]);
}

// -------- fused split-K reduce + residual + bias -> x2 (fp32) + LN -> h (bf16)
__global__ __launch_bounds__(256) void redln_kernel(
    const float* __restrict__ P0, const float* __restrict__ P1,
    const float* __restrict__ bias, const float* __restrict__ res,
    float* __restrict__ x2, const float* __restrict__ lnw,
    const float* __restrict__ lnb, u16* __restrict__ y) {
  int row = blockIdx.x;
  int t = threadIdx.x;
  size_t off = (size_t)row * DIM;
  float v[3];
#pragma unroll
  for (int k = 0; k < 3; ++k) {
    int c = t + k * 256;
    v[k] = P0[off + c] + P1[off + c] + bias[c] + res[off + c];
    x2[off + c] = v[k];
  }
  float s = v[0] + v[1] + v[2];
  float q = v[0] * v[0] + v[1] * v[1] + v[2] * v[2];
  for (int o = 32; o > 0; o >>= 1) {
    s += __shfl_down(s, o, 64);
    q += __shfl_down(q, o, 64);
  }
  __shared__ float ws_[4], wq_[4], mb[2];
  int wid = t >> 6;
  if ((t & 63) == 0) { ws_[wid] = s; wq_[wid] = q; }
  __syncthreads();
  if (t == 0) {
    float S = ws_[0] + ws_[1] + ws_[2] + ws_[3];
    float Q = wq_[0] + wq_[1] + wq_[2] + wq_[3];
    float mean = S * (1.0f / DIM);
    float var = Q * (1.0f / DIM) - mean * mean;
    mb[0] = mean;
    mb[1] = rsqrtf(var + 1e-5f);
  }
  __syncthreads();
  float mean = mb[0], rstd = mb[1];
#pragma unroll
  for (int k = 0; k < 3; ++k) {
    int c = t + k * 256;
    y[off + c] = f2bf((v[k] - mean) * rstd * lnw[c] + lnb[c]);
  }
}

// ---------------- all 4 weight converts in one launch (dims compile-time) ----
__global__ __launch_bounds__(256) void wcvt_all(
    const float* __restrict__ W0, const float* __restrict__ W1,
    const float* __restrict__ W2, const float* __restrict__ W3,
    u16* __restrict__ T0, u16* __restrict__ T1,
    u16* __restrict__ T2, u16* __restrict__ T3) {
  int id = blockIdx.x;
  const float* W; u16* Wt; int K, N, local;
  if (id < 1728)      { W = W0; Wt = T0; K = 768;  N = 2304; local = id; }
  else if (id < 2304) { W = W1; Wt = T1; K = 768;  N = 768;  local = id - 1728; }
  else if (id < 4608) { W = W2; Wt = T2; K = 768;  N = 3072; local = id - 2304; }
  else                { W = W3; Wt = T3; K = 3072; N = 768;  local = id - 4608; }
  int ntiles = N / 32;
  int n0 = (local % ntiles) * 32, k0 = (local / ntiles) * 32;
  __shared__ float tile[32][33];
  int tid = threadIdx.x;
  int c = tid & 31, r8 = tid >> 5;
#pragma unroll
  for (int p = 0; p < 4; ++p) {
    int k = r8 + p * 8;
    tile[k][c] = W[(size_t)(k0 + k) * N + n0 + c];
  }
  __syncthreads();
#pragma unroll
  for (int p = 0; p < 4; ++p) {
    int n = r8 + p * 8;
    Wt[(size_t)(n0 + n) * K + k0 + c] = f2bf(tile[c][n]);
  }
}

// ---------------- V transpose: qkvB V-slice -> vT[b][v][j] ----------------
__global__ __launch_bounds__(256) void vtr_kernel(const u16* __restrict__ qkvB,
                                                  u16* __restrict__ vT) {
  __shared__ u16 tile[32][33];
  int v0 = blockIdx.x * 32, j0 = blockIdx.y * 32, b = blockIdx.z;
  int tid = threadIdx.x;
  int c = tid & 31, r8 = tid >> 5;
#pragma unroll
  for (int p = 0; p < 4; ++p) {
    int r = r8 + p * 8;
    tile[r][c] = qkvB[((size_t)(b * SEQ + j0 + r)) * 2304 + 1536 + v0 + c];
  }
  __syncthreads();
#pragma unroll
  for (int p = 0; p < 4; ++p) {
    int r = r8 + p * 8;
    vT[((size_t)(b * 768 + v0 + r)) * SEQ + j0 + c] = tile[c][r];
  }
}

// ---------------- bf16 MFMA GEMM (full-K): Cb = act(A * Bt^T + bias) --------
// R8: R6 schedule (BK=32, per-32k counted-vmcnt cadence — the proven 270 µs
// config; R7's quad-buffer hit 64 KB LDS -> 2 blocks/CU and regressed) with a
// THIRD buffer: LDS 48 KB (cap 3 blocks/CU == the grid-imposed residency, so
// zero occupancy cost) and prefetch distance 2 — tile t+1's DMAs now get ~2
// k-steps (~600+ cyc) in flight vs ~1 (~300), covering L2 latency.
// Per iter t: compute buf[t%3]; barrier A; stage t+3 -> buf[t%3];
// vmcnt(8) retires exactly t+1's 4 loads (outstanding = t+1,t+2,t+3 = 12);
// barrier B. Tail: vmcnt(4) then vmcnt(0). Swizzle identical to R6.
__global__ __launch_bounds__(256) void bgemm_kernel(
    const u16* __restrict__ A, const u16* __restrict__ Bt,
    const float* __restrict__ bias, u16* __restrict__ Cb,
    int M, int N, int K, int act, int scaleq) {
  __shared__ __align__(16) u16 Asl[3][128 * 32];
  __shared__ __align__(16) u16 Bsl[3][128 * 32];
  int nwg = gridDim.x * gridDim.y;
  int bid = blockIdx.y * gridDim.x + blockIdx.x;
  int swz = (bid & 7) * (nwg >> 3) + (bid >> 3);
  int bx = swz % gridDim.x, by = swz / gridDim.x;
  int tid = threadIdx.x;
  int lane = tid & 63, wave = tid >> 6;
  int wm = wave >> 1, wn = wave & 1;
  int bm = by * 128, bn = bx * 128;
  int l15 = lane & 15, quad = lane >> 4;
  int srow4 = lane >> 2;                        // 0..15: row within 16-row chunk
  int gux = (lane & 3) ^ ((srow4 + (srow4 >> 2)) & 3);  // swizzled global unit

  f32x4 acc[4][4] = {};
  const u16* Ap = A + (size_t)(bm + wave * 16 + srow4) * K + gux * 8;
  const u16* Bp = Bt + (size_t)(bn + wave * 16 + srow4) * K + gux * 8;
  int fx = (l15 + (l15 >> 2)) & 3;              // f(read row)
  int nk = K >> 5;

  auto STAGE = [&](int k0, int sel) {
#pragma unroll
    for (int p = 0; p < 2; ++p)
      gl_lds16(Ap + (size_t)(p * 64) * K + k0, &Asl[sel][(wave * 16 + p * 64) * 32]);
#pragma unroll
    for (int p = 0; p < 2; ++p)
      gl_lds16(Bp + (size_t)(p * 64) * K + k0, &Bsl[sel][(wave * 16 + p * 64) * 32]);
  };

  STAGE(0, 0);
  STAGE(32, 1);
  STAGE(64, 2);
  asm volatile("s_waitcnt vmcnt(8)" ::: "memory");  // tile 0's 4 loads done
  __builtin_amdgcn_s_barrier();

  int sel = 0;
  for (int t = 0; t < nk; ++t) {
    bf16x8 af[4], bfr[4];
#pragma unroll
    for (int i = 0; i < 4; ++i) {
      af[i]  = *(const bf16x8*)&Asl[sel][(wm * 64 + i * 16 + l15) * 32 + (quad ^ fx) * 8];
      bfr[i] = *(const bf16x8*)&Bsl[sel][(wn * 64 + i * 16 + l15) * 32 + (quad ^ fx) * 8];
    }
#pragma unroll
    for (int i = 0; i < 4; ++i)
#pragma unroll
      for (int j = 0; j < 4; ++j)
        acc[i][j] = __builtin_amdgcn_mfma_f32_16x16x32_bf16(af[i], bfr[j], acc[i][j], 0, 0, 0);
    if (t == nk - 1) break;
    __builtin_amdgcn_sched_barrier(0);
    __builtin_amdgcn_s_barrier();        // A: all reads of sel done
    __builtin_amdgcn_sched_barrier(0);
    if (t + 3 < nk) {
      STAGE((t + 3) << 5, sel);
      asm volatile("s_waitcnt vmcnt(8)" ::: "memory");  // retire t+1's 4 loads
    } else if (t + 2 < nk) {
      asm volatile("s_waitcnt vmcnt(4)" ::: "memory");  // retire t+1's 4 loads
    } else {
      asm volatile("s_waitcnt vmcnt(0)" ::: "memory");
    }
    __builtin_amdgcn_sched_barrier(0);
    __builtin_amdgcn_s_barrier();        // B: t+1 data visible
    __builtin_amdgcn_sched_barrier(0);
    sel = (sel == 2) ? 0 : sel + 1;
  }

#pragma unroll
  for (int i = 0; i < 4; ++i) {
#pragma unroll
    for (int j = 0; j < 4; ++j) {
      int n = bn + wn * 64 + j * 16 + l15;
      float bv = bias[n];
      float cs = (scaleq && n < 768) ? KEXPF : 1.0f;
      float val[4];
#pragma unroll
      for (int r = 0; r < 4; ++r) {
        float v = (acc[i][j][r] + bv) * cs;
        val[r] = act ? gelu_t(v) : v;
      }
      u16 c0, c1, c2, c3;
      pk2bf(val[0], val[1], &c0, &c1);
      pk2bf(val[2], val[3], &c2, &c3);
      size_t mbase = (size_t)(bm + wm * 64 + i * 16 + quad * 4) * N + n;
      Cb[mbase]         = c0;
      Cb[mbase + N]     = c1;
      Cb[mbase + 2 * N] = c2;
      Cb[mbase + 3 * N] = c3;
    }
  }
}

// ---------------- bf16 MFMA GEMM, split-K x2, 128x64 tile, BK=64 ------------
// R5 structure kept: counted-vmcnt double-buffer, 48 KB LDS (3 blocks/CU).
__global__ __launch_bounds__(256) void bgemm_splitk(
    const u16* __restrict__ A, const u16* __restrict__ Bt,
    float* __restrict__ P0, float* __restrict__ P1,
    int M, int N, int K) {
  __shared__ __align__(16) u16 Asl[2][128 * 64];
  __shared__ __align__(16) u16 Bsl[2][64 * 64];
  int nwg = gridDim.x * gridDim.y;
  int bid = blockIdx.y * gridDim.x + blockIdx.x;
  int swz = (bid & 7) * (nwg >> 3) + (bid >> 3);
  int bx = swz % gridDim.x, by = swz / gridDim.x;
  int tid = threadIdx.x;
  int lane = tid & 63, wave = tid >> 6;
  int wm = wave >> 1, wn = wave & 1;
  int bm = by * 128, bn = bx * 64;
  int l15 = lane & 15, quad = lane >> 4;
  int sm8 = tid >> 3;
  int kgx = (tid & 7) ^ (sm8 & 7);
  int half = K >> 1;
  int kbeg = blockIdx.z * half;

  f32x4 acc[4][2] = {};
  const u16* Ap = A + (size_t)(bm + sm8) * K + kbeg + kgx * 8;
  const u16* Bp = Bt + (size_t)(bn + sm8) * K + kbeg + kgx * 8;
  int xr = l15 & 7;
  int nk = half >> 6;

  auto STAGE = [&](int k0, int sel) {
#pragma unroll
    for (int p = 0; p < 4; ++p)
      gl_lds16(Ap + (size_t)(p * 32) * K + k0, &Asl[sel][(wave * 8 + p * 32) * 64]);
#pragma unroll
    for (int p = 0; p < 2; ++p)
      gl_lds16(Bp + (size_t)(p * 32) * K + k0, &Bsl[sel][(wave * 8 + p * 32) * 64]);
  };

  STAGE(0, 0);
  if (nk > 1) STAGE(64, 1);
  asm volatile("s_waitcnt vmcnt(6)" ::: "memory");
  __builtin_amdgcn_s_barrier();

  for (int t = 0; t < nk; ++t) {
    int sel = t & 1;
#pragma unroll
    for (int ks = 0; ks < 2; ++ks) {
      int pu = ((ks << 2) + quad) ^ xr;
      bf16x8 af[4], bfr[2];
#pragma unroll
      for (int i = 0; i < 4; ++i)
        af[i] = *(const bf16x8*)&Asl[sel][(wm * 64 + i * 16 + l15) * 64 + pu * 8];
#pragma unroll
      for (int j = 0; j < 2; ++j)
        bfr[j] = *(const bf16x8*)&Bsl[sel][(wn * 32 + j * 16 + l15) * 64 + pu * 8];
#pragma unroll
      for (int i = 0; i < 4; ++i)
#pragma unroll
        for (int j = 0; j < 2; ++j)
          acc[i][j] = __builtin_amdgcn_mfma_f32_16x16x32_bf16(af[i], bfr[j], acc[i][j], 0, 0, 0);
    }
    if (t == nk - 1) break;
    __builtin_amdgcn_sched_barrier(0);
    __builtin_amdgcn_s_barrier();        // A
    __builtin_amdgcn_sched_barrier(0);
    if (t + 2 < nk) {
      STAGE((t + 2) << 6, sel);
      asm volatile("s_waitcnt vmcnt(6)" ::: "memory");
    } else {
      asm volatile("s_waitcnt vmcnt(0)" ::: "memory");
    }
    __builtin_amdgcn_sched_barrier(0);
    __builtin_amdgcn_s_barrier();        // B
    __builtin_amdgcn_sched_barrier(0);
  }

  float* P = blockIdx.z ? P1 : P0;
#pragma unroll
  for (int i = 0; i < 4; ++i) {
#pragma unroll
    for (int j = 0; j < 2; ++j) {
      int n = bn + wn * 32 + j * 16 + l15;
#pragma unroll
      for (int r = 0; r < 4; ++r) {
        int m = bm + wm * 64 + i * 16 + quad * 4 + r;
        P[(size_t)m * N + n] = acc[i][j][r];
      }
    }
  }
}

// ---------------- split-K reduce: O = P0 + P1 + bias + res ------------------
__global__ __launch_bounds__(256) void red_kernel(
    const float* P0, const float* __restrict__ P1,
    const float* __restrict__ bias, const float* __restrict__ res,
    float* O, int Ncols) {
  int i = blockIdx.x * 256 + threadIdx.x;
  float4 a = ((const float4*)P0)[i];
  float4 b = ((const float4*)P1)[i];
  float4 r = ((const float4*)res)[i];
  int col = (i * 4) % Ncols;
  float4 bi = *(const float4*)&bias[col];
  float4 o;
  o.x = a.x + b.x + r.x + bi.x;
  o.y = a.y + b.y + r.y + bi.y;
  o.z = a.z + b.z + r.z + bi.z;
  o.w = a.w + b.w + r.w + bi.w;
  ((float4*)O)[i] = o;
}

// ---------------- 4-wave MFMA flash attention, j-partitioned ----------------
// R4 structure (counted-vmcnt pipeline, ones-MFMA lsum, pre-scaled Q)
// + R5 XCD-aware bijective block swizzle. Unchanged this round.
#define LDP 68
__global__ __launch_bounds__(256, 3) void attn_kernel(const u16* __restrict__ qkv,
                                                      const u16* __restrict__ vT,
                                                      u16* __restrict__ out) {
  __shared__ __align__(16) char arena[40960];
  u16* Qsp = (u16*)arena;                 // 64x64 u16 (8 KB)
  u16* Ksp = (u16*)(arena + 8192);        // [2][64x64] u16 (16 KB)
  u16* Vsp = (u16*)(arena + 24576);       // [2][64x64] u16 (16 KB)

  int nwg = gridDim.x * gridDim.y * gridDim.z;
  int bid = (blockIdx.z * gridDim.y + blockIdx.y) * gridDim.x + blockIdx.x;
  int swz = (bid & 7) * (nwg >> 3) + (bid >> 3);
  int bx = swz % gridDim.x;
  int rem = swz / gridDim.x;
  int h = rem % gridDim.y, b = rem / gridDim.y;

  int tid = threadIdx.x;
  int lane = tid & 63, wave = tid >> 6;
  int l15 = lane & 15, quad = lane >> 4;
  int qt = bx * 64;
  size_t base = (size_t)b * SEQ;
  int srow = lane >> 3;                 // 0..7 within an 8-row DMA chunk
  int sux = (lane & 7) ^ (srow & 7);    // XOR-swizzled global 16B col-unit
  int r0 = wave * 16;                   // this wave's staging row base
  const u16* qbase = qkv + (base + qt) * 2304 + h * HD;
  const u16* kbase = qkv + base * 2304 + 768 + h * HD;
  const u16* vbase = vT + ((size_t)(b * HEADS + h) * HD) * SEQ;

  // stage Q + K/V tile 0 (wave w covers rows r0..r0+15 = two 8-row chunks)
  gl_lds16(qbase + (size_t)(r0 + srow) * 2304 + sux * 8, Qsp + r0 * 64);
  gl_lds16(qbase + (size_t)(r0 + 8 + srow) * 2304 + sux * 8, Qsp + (r0 + 8) * 64);
  gl_lds16(kbase + (size_t)(r0 + srow) * 2304 + sux * 8, Ksp + r0 * 64);
  gl_lds16(kbase + (size_t)(r0 + 8 + srow) * 2304 + sux * 8, Ksp + (r0 + 8) * 64);
  gl_lds16(vbase + (size_t)(r0 + srow) * SEQ + sux * 8, Vsp + r0 * 64);
  gl_lds16(vbase + (size_t)(r0 + 8 + srow) * SEQ + sux * 8, Vsp + (r0 + 8) * 64);
  __syncthreads();   // full drain: tile-0 data + Q visible

  int xr = l15 & 7;
  // Q-frags: q-group g rows g*16+l15, k-step s (32 k each)
  bf16x8 qf[4][2];
#pragma unroll
  for (int g = 0; g < 4; ++g)
#pragma unroll
    for (int s = 0; s < 2; ++s)
      qf[g][s] = *(const bf16x8*)&Qsp[(g * 16 + l15) * 64 + ((s * 4 + quad) ^ xr) * 8];

  // prefetch tile 1 into buf 1 (in flight across tile 0's compute)
  gl_lds16(kbase + (size_t)(64 + r0 + srow) * 2304 + sux * 8, Ksp + 4096 + r0 * 64);
  gl_lds16(kbase + (size_t)(64 + r0 + 8 + srow) * 2304 + sux * 8, Ksp + 4096 + (r0 + 8) * 64);
  gl_lds16(vbase + (size_t)(r0 + srow) * SEQ + 64 + sux * 8, Vsp + 4096 + r0 * 64);
  gl_lds16(vbase + (size_t)(r0 + 8 + srow) * SEQ + 64 + sux * 8, Vsp + 4096 + (r0 + 8) * 64);

  // tile-invariant LDS element offsets
  int koff0 = (wave * 16 + l15) * 64 + ((quad ^ xr)) * 8;
  int koff1 = (wave * 16 + l15) * 64 + (((4 + quad) ^ xr)) * 8;
  int voff[4];
#pragma unroll
  for (int dg = 0; dg < 4; ++dg)
    voff[dg] = (dg * 16 + l15) * 64 + (((2 * wave + (quad >> 1)) ^ xr)) * 8 + (quad & 1) * 4;

  f32x4 oT[4][4] = {};   // [dg][g] : O^T tiles (d rows, q cols), j-partial
  f32x4 oT1[4] = {};     // [g] : ones-row accumulators (stripe row-sums of P)
  const short4v ONES = {(short)0x3F80, (short)0x3F80, (short)0x3F80, (short)0x3F80};
  int buf = 0;

  for (int t = 0; t < 32; ++t) {
    const u16* Kb = Ksp + buf * 4096;
    const u16* Vb = Vsp + buf * 4096;

    // QK^T: S^T[j-stripe 16][q 64] ; lane: j=16w+quad*4+r, q=16g+l15
    f32x4 sT[4] = {};
    __builtin_amdgcn_s_setprio(1);
    {
      bf16x8 ak = *(const bf16x8*)&Kb[koff0];
#pragma unroll
      for (int g = 0; g < 4; ++g)
        sT[g] = __builtin_amdgcn_mfma_f32_16x16x32_bf16(ak, qf[g][0], sT[g], 0, 0, 0);
      bf16x8 ak1 = *(const bf16x8*)&Kb[koff1];
#pragma unroll
      for (int g = 0; g < 4; ++g)
        sT[g] = __builtin_amdgcn_mfma_f32_16x16x32_bf16(ak1, qf[g][1], sT[g], 0, 0, 0);
    }
    __builtin_amdgcn_s_setprio(0);

    // softmax (max-free, Q pre-scaled): p = 2^s ; pack -> x16 B-frags
    short4v pb[4];
#pragma unroll
    for (int g = 0; g < 4; ++g) {
      float p0 = __builtin_amdgcn_exp2f(sT[g][0]);
      float p1 = __builtin_amdgcn_exp2f(sT[g][1]);
      float p2 = __builtin_amdgcn_exp2f(sT[g][2]);
      float p3 = __builtin_amdgcn_exp2f(sT[g][3]);
      union { unsigned u[2]; short4v s; } cv;
      cv.u[0] = pku32(p0, p1);
      cv.u[1] = pku32(p2, p3);
      pb[g] = cv.s;
    }

    // PV: oT[dg][g] += V^T[d-block][stripe] * P^T[stripe][q-group]
    // + ones row: oT1[g] += 1s * P^T  (stripe row-sum -> l partials)
    short4v av[4];
#pragma unroll
    for (int dg = 0; dg < 4; ++dg)
      av[dg] = *(const short4v*)&Vb[voff[dg]];
    __builtin_amdgcn_s_setprio(1);
#pragma unroll
    for (int dg = 0; dg < 4; ++dg)
#pragma unroll
      for (int g = 0; g < 4; ++g)
        oT[dg][g] = __builtin_amdgcn_mfma_f32_16x16x16bf16_1k(av[dg], pb[g], oT[dg][g], 0, 0, 0);
#pragma unroll
    for (int g = 0; g < 4; ++g)
      oT1[g] = __builtin_amdgcn_mfma_f32_16x16x16bf16_1k(ONES, pb[g], oT1[g], 0, 0, 0);
    __builtin_amdgcn_s_setprio(0);

    __builtin_amdgcn_sched_barrier(0);
    __builtin_amdgcn_s_barrier();          // A: all reads of buf done
    __builtin_amdgcn_sched_barrier(0);
    if (t < 30) {  // prefetch tile t+2 into the buffer just freed
      size_t kt2 = (size_t)(t + 2) * 64;
      u16* Kd = Ksp + buf * 4096;
      u16* Vd = Vsp + buf * 4096;
      gl_lds16(kbase + (kt2 + r0 + srow) * 2304 + sux * 8, Kd + r0 * 64);
      gl_lds16(kbase + (kt2 + r0 + 8 + srow) * 2304 + sux * 8, Kd + (r0 + 8) * 64);
      gl_lds16(vbase + (size_t)(r0 + srow) * SEQ + kt2 + sux * 8, Vd + r0 * 64);
      gl_lds16(vbase + (size_t)(r0 + 8 + srow) * SEQ + kt2 + sux * 8, Vd + (r0 + 8) * 64);
      asm volatile("s_waitcnt vmcnt(4)" ::: "memory");  // retire t+1's 4 loads
    } else {
      asm volatile("s_waitcnt vmcnt(0)" ::: "memory");
    }
    __builtin_amdgcn_sched_barrier(0);
    __builtin_amdgcn_s_barrier();          // B: t+1 data visible to all waves
    __builtin_amdgcn_sched_barrier(0);
    buf ^= 1;
  }

  // ---- epilogue: cross-wave reduce of j-partial O^T + l, then write ----
  // (barriers A+B of t=31 guarantee all K/V reads done -> arena reusable)
  float* LDSw = (float*)arena;             // [4 waves][16 d][LDP] f32 (17408 B)
  float* lsd  = (float*)(arena + 17408);   // [4 waves][4 g][16] f32 (1 KB)
  if (lane < 16) {
#pragma unroll
    for (int g = 0; g < 4; ++g) lsd[wave * 64 + g * 16 + lane] = oT1[g][0];
  }
  float linv = 0.f;
#pragma unroll
  for (int dg = 0; dg < 4; ++dg) {
    // write phase: wave u writes its oT tiles for d-chunk dg
#pragma unroll
    for (int g = 0; g < 4; ++g)
#pragma unroll
      for (int r = 0; r < 4; ++r)
        LDSw[wave * (16 * LDP) + (quad * 4 + r) * LDP + g * 16 + l15] = oT[dg][g][r];
    __syncthreads();
    if (dg == 0) {
      float L = lsd[wave * 16 + l15] + lsd[64 + wave * 16 + l15] +
                lsd[128 + wave * 16 + l15] + lsd[192 + wave * 16 + l15];
      linv = 1.0f / L;
    }
    // sum phase: thread (wave,l15,quad) -> q = wave*16+l15, d = dg*16+quad*4+i
    float sv[4];
#pragma unroll
    for (int i = 0; i < 4; ++i) {
      int dloc = quad * 4 + i;
      float a = LDSw[dloc * LDP + wave * 16 + l15] +
                LDSw[1 * (16 * LDP) + dloc * LDP + wave * 16 + l15] +
                LDSw[2 * (16 * LDP) + dloc * LDP + wave * 16 + l15] +
                LDSw[3 * (16 * LDP) + dloc * LDP + wave * 16 + l15];
      sv[i] = a * linv;
    }
    size_t addr = (base + qt + wave * 16 + l15) * DIM + h * HD + dg * 16 + quad * 4;
    uint2 pk;
    pk.x = pku32(sv[0], sv[1]);
    pk.y = pku32(sv[2], sv[3]);
    *(uint2*)&out[addr] = pk;
    __syncthreads();  // before next chunk reuses LDSw
  }
}

extern "C" void kernel_launch(void* const* d_in, const int* in_sizes, int n_in,
                              void* d_out, int out_size, void* d_ws, size_t ws_size,
                              hipStream_t stream) {
  const float* x     = (const float*)d_in[0];
  const float* ln1w  = (const float*)d_in[1];
  const float* ln1b  = (const float*)d_in[2];
  const float* qkvw  = (const float*)d_in[3];
  const float* qkvbi = (const float*)d_in[4];
  const float* projw = (const float*)d_in[5];
  const float* projb = (const float*)d_in[6];
  const float* ln2w  = (const float*)d_in[7];
  const float* ln2b  = (const float*)d_in[8];
  const float* l1w   = (const float*)d_in[9];
  const float* l1b   = (const float*)d_in[10];
  const float* l2w   = (const float*)d_in[11];
  const float* l2b   = (const float*)d_in[12];
  float* out = (float*)d_out;

  char* w = (char*)d_ws;
  u16*   h     = (u16*)w;   w += (size_t)NTOK * DIM * 2;          // 6.3 MB
  u16*   qkvB  = (u16*)w;                                         // 18.9 MB (union)
  u16*   mid   = (u16*)w;   w += (size_t)NTOK * 3072 * 2;         // 25.2 MB union
  u16*   attnb = (u16*)w;   w += (size_t)NTOK * DIM * 2;          // 6.3 MB
  float* x2    = (float*)w; w += (size_t)NTOK * DIM * 4;          // 12.6 MB
  u16*   vTb   = (u16*)w;   w += (size_t)NTOK * DIM * 2;          // 6.3 MB
  u16*   qkvwt = (u16*)w;   w += (size_t)DIM * 2304 * 2;
  u16*   projwt= (u16*)w;   w += (size_t)DIM * DIM * 2;
  u16*   l1wt  = (u16*)w;   w += (size_t)DIM * 3072 * 2;
  u16*   l2wt  = (u16*)w;   w += (size_t)3072 * DIM * 2;
  float* Pbuf  = (float*)w; w += (size_t)NTOK * DIM * 4;          // 12.6 MB (split-K P1)

  wcvt_all<<<6912, 256, 0, stream>>>(qkvw, projw, l1w, l2w,
                                     qkvwt, projwt, l1wt, l2wt);

  ln_kernel<<<NTOK, 256, 0, stream>>>(x, ln1w, ln1b, h);
  bgemm_kernel<<<dim3(2304 / 128, NTOK / 128), 256, 0, stream>>>(
      h, qkvwt, qkvbi, qkvB, NTOK, 2304, DIM, 0, 1);
  vtr_kernel<<<dim3(768 / 32, SEQ / 32, 2), 256, 0, stream>>>(qkvB, vTb);
  attn_kernel<<<dim3(SEQ / 64, HEADS, 2), 256, 0, stream>>>(qkvB, vTb, attnb);

  // proj: split-K x2 -> x2 + Pbuf; fused reduce(+bias+x residual) + LN2
  bgemm_splitk<<<dim3(DIM / 64, NTOK / 128, 2), 256, 0, stream>>>(
      attnb, projwt, x2, Pbuf, NTOK, DIM, DIM);
  redln_kernel<<<NTOK, 256, 0, stream>>>(x2, Pbuf, projb, x, x2, ln2w, ln2b, h);

  bgemm_kernel<<<dim3(3072 / 128, NTOK / 128), 256, 0, stream>>>(
      h, l1wt, l1b, mid, NTOK, 3072, DIM, 1, 0);

  // lin2: split-K x2 -> out + Pbuf; reduce adds bias + x2 residual
  bgemm_splitk<<<dim3(DIM / 64, NTOK / 128, 2), 256, 0, stream>>>(
      mid, l2wt, out, Pbuf, NTOK, DIM, 3072);
  red_kernel<<<NTOK * DIM / 1024, 256, 0, stream>>>(out, Pbuf, l2b, x2, out, DIM);
}

// Round 9
// 266.640 us; speedup vs baseline: 1.0684x; 1.0120x over previous
//
#include <hip/hip_runtime.h>
#include <hip/hip_bf16.h>
#include <math.h>

#define DIM 768
#define NTOK 4096   // B*N = 2*2048
#define SEQ 2048
#define HEADS 12
#define HD 64

using bf16x8 = __attribute__((ext_vector_type(8))) __bf16;
using bf16x4 = __attribute__((ext_vector_type(4))) __bf16;
using short4v = __attribute__((ext_vector_type(4))) short;
using f32x4  = __attribute__((ext_vector_type(4))) float;
typedef unsigned short u16;

#define KEXPF 0.18033688011112042f  // log2(e)/8

__device__ inline u16 f2bf(float f) {
  union { float f; unsigned u; } v; v.f = f;
  unsigned r = v.u + 0x7fffu + ((v.u >> 16) & 1u);  // RNE
  return (u16)(r >> 16);
}

// packed f32x2 -> bf16x2 (v_cvt_pk_bf16_f32)
__device__ inline void pk2bf(float a, float b, u16* o0, u16* o1) {
  union { __hip_bfloat162 h; u16 u[2]; } cv;
  cv.h = __float22bfloat162_rn(make_float2(a, b));
  *o0 = cv.u[0];
  *o1 = cv.u[1];
}

// packed f32x2 -> one u32 of 2 bf16 (lo = a, hi = b)
__device__ inline unsigned pku32(float a, float b) {
  union { __hip_bfloat162 h; unsigned u; } cv;
  cv.h = __float22bfloat162_rn(make_float2(a, b));
  return cv.u;
}

// GELU, sigmoid form: x*sigmoid(1.5957691x + 0.0713548x^3); |err| < ~3e-3.
__device__ inline float gelu_t(float x) {
  float z = x * (1.5957691216f + 0.0713548162f * x * x);
  return x / (1.0f + __expf(-z));
}

// async global->LDS DMA, 16 B per lane; LDS dest = wave-uniform base + lane*16
__device__ inline void gl_lds16(const u16* g, u16* l) {
  __builtin_amdgcn_global_load_lds(
      (const __attribute__((address_space(1))) unsigned int*)g,
      (__attribute__((address_space(3))) unsigned int*)l, 16, 0, 0);
}

// ---------------- LayerNorm: fp32 in -> bf16 out ----------------
__global__ __launch_bounds__(256) void ln_kernel(const float* __restrict__ x,
                                                 const float* __restrict__ w,
                                                 const float* __restrict__ b,
                                                 u16* __restrict__ y) {
  int row = blockIdx.x;
  int t = threadIdx.x;
  const float* xr = x + (size_t)row * DIM;
  float v0 = xr[t], v1 = xr[t + 256], v2 = xr[t + 512];
  float s = v0 + v1 + v2;
  float q = v0 * v0 + v1 * v1 + v2 * v2;
  for (int o = 32; o > 0; o >>= 1) {
    s += __shfl_down(s, o, 64);
    q += __shfl_down(q, o, 64);
  }
  __shared__ float ws_[4], wq_[4], mb[2];
  int wid = t >> 6;
  if ((t & 63) == 0) { ws_[wid] = s; wq_[wid] = q; }
  __syncthreads();
  if (t == 0) {
    float S = ws_[0] + ws_[1] + ws_[2] + ws_[3];
    float Q = wq_[0] + wq_[1] + wq_[2] + wq_[3];
    float mean = S * (1.0f / DIM);
    float var = Q * (1.0f / DIM) - mean * mean;
    mb[0] = mean;
    mb[1] = rsqrtf(var + 1e-5f);
  }
  __syncthreads();
  float mean = mb[0], rstd = mb[1];
  u16* yr = y + (size_t)row * DIM;
  yr[t]       = f2bf((v0 - mean) * rstd * w[t]       + b[t]);
  yr[t + 256] = f2bf((v1 - mean) * rstd * w[t + 256] + b[t + 256]);
  yr[t + 512] = f2bf((v2 - mean) * rstd * w[t + 512] + b[t + 512]);
}

// -------- fused split-K reduce + residual + bias -> x2 (fp32) + LN -> h (bf16)
__global__ __launch_bounds__(256) void redln_kernel(
    const float* __restrict__ P0, const float* __restrict__ P1,
    const float* __restrict__ bias, const float* __restrict__ res,
    float* __restrict__ x2, const float* __restrict__ lnw,
    const float* __restrict__ lnb, u16* __restrict__ y) {
  int row = blockIdx.x;
  int t = threadIdx.x;
  size_t off = (size_t)row * DIM;
  float v[3];
#pragma unroll
  for (int k = 0; k < 3; ++k) {
    int c = t + k * 256;
    v[k] = P0[off + c] + P1[off + c] + bias[c] + res[off + c];
    x2[off + c] = v[k];
  }
  float s = v[0] + v[1] + v[2];
  float q = v[0] * v[0] + v[1] * v[1] + v[2] * v[2];
  for (int o = 32; o > 0; o >>= 1) {
    s += __shfl_down(s, o, 64);
    q += __shfl_down(q, o, 64);
  }
  __shared__ float ws_[4], wq_[4], mb[2];
  int wid = t >> 6;
  if ((t & 63) == 0) { ws_[wid] = s; wq_[wid] = q; }
  __syncthreads();
  if (t == 0) {
    float S = ws_[0] + ws_[1] + ws_[2] + ws_[3];
    float Q = wq_[0] + wq_[1] + wq_[2] + wq_[3];
    float mean = S * (1.0f / DIM);
    float var = Q * (1.0f / DIM) - mean * mean;
    mb[0] = mean;
    mb[1] = rsqrtf(var + 1e-5f);
  }
  __syncthreads();
  float mean = mb[0], rstd = mb[1];
#pragma unroll
  for (int k = 0; k < 3; ++k) {
    int c = t + k * 256;
    y[off + c] = f2bf((v[k] - mean) * rstd * lnw[c] + lnb[c]);
  }
}

// ---------------- all 4 weight converts in one launch (dims compile-time) ----
__global__ __launch_bounds__(256) void wcvt_all(
    const float* __restrict__ W0, const float* __restrict__ W1,
    const float* __restrict__ W2, const float* __restrict__ W3,
    u16* __restrict__ T0, u16* __restrict__ T1,
    u16* __restrict__ T2, u16* __restrict__ T3) {
  int id = blockIdx.x;
  const float* W; u16* Wt; int K, N, local;
  if (id < 1728)      { W = W0; Wt = T0; K = 768;  N = 2304; local = id; }
  else if (id < 2304) { W = W1; Wt = T1; K = 768;  N = 768;  local = id - 1728; }
  else if (id < 4608) { W = W2; Wt = T2; K = 768;  N = 3072; local = id - 2304; }
  else                { W = W3; Wt = T3; K = 3072; N = 768;  local = id - 4608; }
  int ntiles = N / 32;
  int n0 = (local % ntiles) * 32, k0 = (local / ntiles) * 32;
  __shared__ float tile[32][33];
  int tid = threadIdx.x;
  int c = tid & 31, r8 = tid >> 5;
#pragma unroll
  for (int p = 0; p < 4; ++p) {
    int k = r8 + p * 8;
    tile[k][c] = W[(size_t)(k0 + k) * N + n0 + c];
  }
  __syncthreads();
#pragma unroll
  for (int p = 0; p < 4; ++p) {
    int n = r8 + p * 8;
    Wt[(size_t)(n0 + n) * K + k0 + c] = f2bf(tile[c][n]);
  }
}

// ---------------- V transpose: qkvB V-slice -> vT[b][v][j] ----------------
__global__ __launch_bounds__(256) void vtr_kernel(const u16* __restrict__ qkvB,
                                                  u16* __restrict__ vT) {
  __shared__ u16 tile[32][33];
  int v0 = blockIdx.x * 32, j0 = blockIdx.y * 32, b = blockIdx.z;
  int tid = threadIdx.x;
  int c = tid & 31, r8 = tid >> 5;
#pragma unroll
  for (int p = 0; p < 4; ++p) {
    int r = r8 + p * 8;
    tile[r][c] = qkvB[((size_t)(b * SEQ + j0 + r)) * 2304 + 1536 + v0 + c];
  }
  __syncthreads();
#pragma unroll
  for (int p = 0; p < 4; ++p) {
    int r = r8 + p * 8;
    vT[((size_t)(b * 768 + v0 + r)) * SEQ + j0 + c] = tile[c][r];
  }
}

// ---------------- bf16 MFMA GEMM (full-K): Cb = act(A * Bt^T + bias) --------
// R8 config (neutral vs R6, kept): BK=32 triple-buffer, 48 KB LDS, counted
// vmcnt, prefetch distance 2. XCD-aware bijective swizzle.
__global__ __launch_bounds__(256) void bgemm_kernel(
    const u16* __restrict__ A, const u16* __restrict__ Bt,
    const float* __restrict__ bias, u16* __restrict__ Cb,
    int M, int N, int K, int act, int scaleq) {
  __shared__ __align__(16) u16 Asl[3][128 * 32];
  __shared__ __align__(16) u16 Bsl[3][128 * 32];
  int nwg = gridDim.x * gridDim.y;
  int bid = blockIdx.y * gridDim.x + blockIdx.x;
  int swz = (bid & 7) * (nwg >> 3) + (bid >> 3);
  int bx = swz % gridDim.x, by = swz / gridDim.x;
  int tid = threadIdx.x;
  int lane = tid & 63, wave = tid >> 6;
  int wm = wave >> 1, wn = wave & 1;
  int bm = by * 128, bn = bx * 128;
  int l15 = lane & 15, quad = lane >> 4;
  int srow4 = lane >> 2;                        // 0..15: row within 16-row chunk
  int gux = (lane & 3) ^ ((srow4 + (srow4 >> 2)) & 3);  // swizzled global unit

  f32x4 acc[4][4] = {};
  const u16* Ap = A + (size_t)(bm + wave * 16 + srow4) * K + gux * 8;
  const u16* Bp = Bt + (size_t)(bn + wave * 16 + srow4) * K + gux * 8;
  int fx = (l15 + (l15 >> 2)) & 3;              // f(read row)
  int nk = K >> 5;

  auto STAGE = [&](int k0, int sel) {
#pragma unroll
    for (int p = 0; p < 2; ++p)
      gl_lds16(Ap + (size_t)(p * 64) * K + k0, &Asl[sel][(wave * 16 + p * 64) * 32]);
#pragma unroll
    for (int p = 0; p < 2; ++p)
      gl_lds16(Bp + (size_t)(p * 64) * K + k0, &Bsl[sel][(wave * 16 + p * 64) * 32]);
  };

  STAGE(0, 0);
  STAGE(32, 1);
  STAGE(64, 2);
  asm volatile("s_waitcnt vmcnt(8)" ::: "memory");  // tile 0's 4 loads done
  __builtin_amdgcn_s_barrier();

  int sel = 0;
  for (int t = 0; t < nk; ++t) {
    bf16x8 af[4], bfr[4];
#pragma unroll
    for (int i = 0; i < 4; ++i) {
      af[i]  = *(const bf16x8*)&Asl[sel][(wm * 64 + i * 16 + l15) * 32 + (quad ^ fx) * 8];
      bfr[i] = *(const bf16x8*)&Bsl[sel][(wn * 64 + i * 16 + l15) * 32 + (quad ^ fx) * 8];
    }
#pragma unroll
    for (int i = 0; i < 4; ++i)
#pragma unroll
      for (int j = 0; j < 4; ++j)
        acc[i][j] = __builtin_amdgcn_mfma_f32_16x16x32_bf16(af[i], bfr[j], acc[i][j], 0, 0, 0);
    if (t == nk - 1) break;
    __builtin_amdgcn_sched_barrier(0);
    __builtin_amdgcn_s_barrier();        // A: all reads of sel done
    __builtin_amdgcn_sched_barrier(0);
    if (t + 3 < nk) {
      STAGE((t + 3) << 5, sel);
      asm volatile("s_waitcnt vmcnt(8)" ::: "memory");  // retire t+1's 4 loads
    } else if (t + 2 < nk) {
      asm volatile("s_waitcnt vmcnt(4)" ::: "memory");  // retire t+1's 4 loads
    } else {
      asm volatile("s_waitcnt vmcnt(0)" ::: "memory");
    }
    __builtin_amdgcn_sched_barrier(0);
    __builtin_amdgcn_s_barrier();        // B: t+1 data visible
    __builtin_amdgcn_sched_barrier(0);
    sel = (sel == 2) ? 0 : sel + 1;
  }

#pragma unroll
  for (int i = 0; i < 4; ++i) {
#pragma unroll
    for (int j = 0; j < 4; ++j) {
      int n = bn + wn * 64 + j * 16 + l15;
      float bv = bias[n];
      float cs = (scaleq && n < 768) ? KEXPF : 1.0f;
      float val[4];
#pragma unroll
      for (int r = 0; r < 4; ++r) {
        float v = (acc[i][j][r] + bv) * cs;
        val[r] = act ? gelu_t(v) : v;
      }
      u16 c0, c1, c2, c3;
      pk2bf(val[0], val[1], &c0, &c1);
      pk2bf(val[2], val[3], &c2, &c3);
      size_t mbase = (size_t)(bm + wm * 64 + i * 16 + quad * 4) * N + n;
      Cb[mbase]         = c0;
      Cb[mbase + N]     = c1;
      Cb[mbase + 2 * N] = c2;
      Cb[mbase + 3 * N] = c3;
    }
  }
}

// ---------------- bf16 MFMA GEMM, split-K x2, 128x64 tile, BK=64 ------------
// R5 structure kept: counted-vmcnt double-buffer, 48 KB LDS (3 blocks/CU).
__global__ __launch_bounds__(256) void bgemm_splitk(
    const u16* __restrict__ A, const u16* __restrict__ Bt,
    float* __restrict__ P0, float* __restrict__ P1,
    int M, int N, int K) {
  __shared__ __align__(16) u16 Asl[2][128 * 64];
  __shared__ __align__(16) u16 Bsl[2][64 * 64];
  int nwg = gridDim.x * gridDim.y;
  int bid = blockIdx.y * gridDim.x + blockIdx.x;
  int swz = (bid & 7) * (nwg >> 3) + (bid >> 3);
  int bx = swz % gridDim.x, by = swz / gridDim.x;
  int tid = threadIdx.x;
  int lane = tid & 63, wave = tid >> 6;
  int wm = wave >> 1, wn = wave & 1;
  int bm = by * 128, bn = bx * 64;
  int l15 = lane & 15, quad = lane >> 4;
  int sm8 = tid >> 3;
  int kgx = (tid & 7) ^ (sm8 & 7);
  int half = K >> 1;
  int kbeg = blockIdx.z * half;

  f32x4 acc[4][2] = {};
  const u16* Ap = A + (size_t)(bm + sm8) * K + kbeg + kgx * 8;
  const u16* Bp = Bt + (size_t)(bn + sm8) * K + kbeg + kgx * 8;
  int xr = l15 & 7;
  int nk = half >> 6;

  auto STAGE = [&](int k0, int sel) {
#pragma unroll
    for (int p = 0; p < 4; ++p)
      gl_lds16(Ap + (size_t)(p * 32) * K + k0, &Asl[sel][(wave * 8 + p * 32) * 64]);
#pragma unroll
    for (int p = 0; p < 2; ++p)
      gl_lds16(Bp + (size_t)(p * 32) * K + k0, &Bsl[sel][(wave * 8 + p * 32) * 64]);
  };

  STAGE(0, 0);
  if (nk > 1) STAGE(64, 1);
  asm volatile("s_waitcnt vmcnt(6)" ::: "memory");
  __builtin_amdgcn_s_barrier();

  for (int t = 0; t < nk; ++t) {
    int sel = t & 1;
#pragma unroll
    for (int ks = 0; ks < 2; ++ks) {
      int pu = ((ks << 2) + quad) ^ xr;
      bf16x8 af[4], bfr[2];
#pragma unroll
      for (int i = 0; i < 4; ++i)
        af[i] = *(const bf16x8*)&Asl[sel][(wm * 64 + i * 16 + l15) * 64 + pu * 8];
#pragma unroll
      for (int j = 0; j < 2; ++j)
        bfr[j] = *(const bf16x8*)&Bsl[sel][(wn * 32 + j * 16 + l15) * 64 + pu * 8];
#pragma unroll
      for (int i = 0; i < 4; ++i)
#pragma unroll
        for (int j = 0; j < 2; ++j)
          acc[i][j] = __builtin_amdgcn_mfma_f32_16x16x32_bf16(af[i], bfr[j], acc[i][j], 0, 0, 0);
    }
    if (t == nk - 1) break;
    __builtin_amdgcn_sched_barrier(0);
    __builtin_amdgcn_s_barrier();        // A
    __builtin_amdgcn_sched_barrier(0);
    if (t + 2 < nk) {
      STAGE((t + 2) << 6, sel);
      asm volatile("s_waitcnt vmcnt(6)" ::: "memory");
    } else {
      asm volatile("s_waitcnt vmcnt(0)" ::: "memory");
    }
    __builtin_amdgcn_sched_barrier(0);
    __builtin_amdgcn_s_barrier();        // B
    __builtin_amdgcn_sched_barrier(0);
  }

  float* P = blockIdx.z ? P1 : P0;
#pragma unroll
  for (int i = 0; i < 4; ++i) {
#pragma unroll
    for (int j = 0; j < 2; ++j) {
      int n = bn + wn * 32 + j * 16 + l15;
#pragma unroll
      for (int r = 0; r < 4; ++r) {
        int m = bm + wm * 64 + i * 16 + quad * 4 + r;
        P[(size_t)m * N + n] = acc[i][j][r];
      }
    }
  }
}

// ---------------- split-K reduce: O = P0 + P1 + bias + res ------------------
__global__ __launch_bounds__(256) void red_kernel(
    const float* P0, const float* __restrict__ P1,
    const float* __restrict__ bias, const float* __restrict__ res,
    float* O, int Ncols) {
  int i = blockIdx.x * 256 + threadIdx.x;
  float4 a = ((const float4*)P0)[i];
  float4 b = ((const float4*)P1)[i];
  float4 r = ((const float4*)res)[i];
  int col = (i * 4) % Ncols;
  float4 bi = *(const float4*)&bias[col];
  float4 o;
  o.x = a.x + b.x + r.x + bi.x;
  o.y = a.y + b.y + r.y + bi.y;
  o.z = a.z + b.z + r.z + bi.z;
  o.w = a.w + b.w + r.w + bi.w;
  ((float4*)O)[i] = o;
}

// ---------------- 8-wave MFMA flash attention, (ws,js)-partitioned ----------
// R9: attn was wave-starved (grid 768 = 3 blocks/CU, 4 waves/block -> 12
// waves/CU, 3/SIMD; MfmaUtil 39 + VALU 43, nothing saturated). Same LDS
// (40960), same algorithm, but 8 waves (512 thr): wave=(ws,js); js owns the
// 16-row j-stripe (as before), ws owns a 32-q half. Per-wave work halves,
// waves/CU doubles to 24 (6/SIMD). K-frag reads duplicate x2 across ws (LDS
// pipe has headroom). Staging: 1 DMA/wave/tensor (8 rows); in-loop vmcnt(2).
// Counted-vmcnt pipeline, ones-MFMA lsum, pre-scaled Q, XCD swizzle kept.
#define LQP 33
__global__ __launch_bounds__(512, 6) void attn_kernel(const u16* __restrict__ qkv,
                                                      const u16* __restrict__ vT,
                                                      u16* __restrict__ out) {
  __shared__ __align__(16) char arena[40960];
  u16* Qsp = (u16*)arena;                 // 64x64 u16 (8 KB)
  u16* Ksp = (u16*)(arena + 8192);        // [2][64x64] u16 (16 KB)
  u16* Vsp = (u16*)(arena + 24576);       // [2][64x64] u16 (16 KB)

  int nwg = gridDim.x * gridDim.y * gridDim.z;
  int bid = (blockIdx.z * gridDim.y + blockIdx.y) * gridDim.x + blockIdx.x;
  int swz = (bid & 7) * (nwg >> 3) + (bid >> 3);
  int bx = swz % gridDim.x;
  int rem = swz / gridDim.x;
  int h = rem % gridDim.y, b = rem / gridDim.y;

  int tid = threadIdx.x;
  int lane = tid & 63, wave = tid >> 6;   // 8 waves
  int ws = wave & 1, js = wave >> 1;      // q-half, j-stripe
  int l15 = lane & 15, quad = lane >> 4;
  int qt = bx * 64;
  size_t base = (size_t)b * SEQ;
  int srow = lane >> 3;                 // 0..7 within an 8-row DMA chunk
  int sux = (lane & 7) ^ (srow & 7);    // XOR-swizzled global 16B col-unit
  int r0 = wave * 8;                    // this wave's staging row base (8 rows)
  const u16* qbase = qkv + (base + qt) * 2304 + h * HD;
  const u16* kbase = qkv + base * 2304 + 768 + h * HD;
  const u16* vbase = vT + ((size_t)(b * HEADS + h) * HD) * SEQ;

  // stage Q + K/V tile 0 (wave w covers rows r0..r0+7 = one 8-row chunk)
  gl_lds16(qbase + (size_t)(r0 + srow) * 2304 + sux * 8, Qsp + r0 * 64);
  gl_lds16(kbase + (size_t)(r0 + srow) * 2304 + sux * 8, Ksp + r0 * 64);
  gl_lds16(vbase + (size_t)(r0 + srow) * SEQ + sux * 8, Vsp + r0 * 64);
  __syncthreads();   // full drain: tile-0 data + Q visible

  int xr = l15 & 7;
  // Q-frags: q-group g (rows ws*32 + g*16 + l15), k-step s (32 k each)
  bf16x8 qf[2][2];
#pragma unroll
  for (int g = 0; g < 2; ++g)
#pragma unroll
    for (int s = 0; s < 2; ++s)
      qf[g][s] = *(const bf16x8*)&Qsp[(ws * 32 + g * 16 + l15) * 64 + ((s * 4 + quad) ^ xr) * 8];

  // prefetch tile 1 into buf 1 (in flight across tile 0's compute)
  gl_lds16(kbase + (size_t)(64 + r0 + srow) * 2304 + sux * 8, Ksp + 4096 + r0 * 64);
  gl_lds16(vbase + (size_t)(r0 + srow) * SEQ + 64 + sux * 8, Vsp + 4096 + r0 * 64);

  // tile-invariant LDS element offsets (stripe js)
  int koff0 = (js * 16 + l15) * 64 + ((quad ^ xr)) * 8;
  int koff1 = (js * 16 + l15) * 64 + (((4 + quad) ^ xr)) * 8;
  int voff[4];
#pragma unroll
  for (int dg = 0; dg < 4; ++dg)
    voff[dg] = (dg * 16 + l15) * 64 + (((2 * js + (quad >> 1)) ^ xr)) * 8 + (quad & 1) * 4;

  f32x4 oT[4][2] = {};   // [dg][g] : O^T tiles (d rows, q cols), js-partial
  f32x4 oT1[2] = {};     // [g] : ones-row accumulators (stripe row-sums of P)
  const short4v ONES = {(short)0x3F80, (short)0x3F80, (short)0x3F80, (short)0x3F80};
  int buf = 0;

  for (int t = 0; t < 32; ++t) {
    const u16* Kb = Ksp + buf * 4096;
    const u16* Vb = Vsp + buf * 4096;

    // QK^T: S^T[j-stripe 16][q-half 32] ; lane: j=16js+quad*4+r, q=ws*32+16g+l15
    f32x4 sT[2] = {};
    __builtin_amdgcn_s_setprio(1);
    {
      bf16x8 ak = *(const bf16x8*)&Kb[koff0];
#pragma unroll
      for (int g = 0; g < 2; ++g)
        sT[g] = __builtin_amdgcn_mfma_f32_16x16x32_bf16(ak, qf[g][0], sT[g], 0, 0, 0);
      bf16x8 ak1 = *(const bf16x8*)&Kb[koff1];
#pragma unroll
      for (int g = 0; g < 2; ++g)
        sT[g] = __builtin_amdgcn_mfma_f32_16x16x32_bf16(ak1, qf[g][1], sT[g], 0, 0, 0);
    }
    __builtin_amdgcn_s_setprio(0);

    // softmax (max-free, Q pre-scaled): p = 2^s ; pack -> x16 B-frags
    short4v pb[2];
#pragma unroll
    for (int g = 0; g < 2; ++g) {
      float p0 = __builtin_amdgcn_exp2f(sT[g][0]);
      float p1 = __builtin_amdgcn_exp2f(sT[g][1]);
      float p2 = __builtin_amdgcn_exp2f(sT[g][2]);
      float p3 = __builtin_amdgcn_exp2f(sT[g][3]);
      union { unsigned u[2]; short4v s; } cv;
      cv.u[0] = pku32(p0, p1);
      cv.u[1] = pku32(p2, p3);
      pb[g] = cv.s;
    }

    // PV: oT[dg][g] += V^T[d-block][stripe] * P^T[stripe][q-group]
    // + ones row: oT1[g] += 1s * P^T  (stripe row-sum -> l partials)
    short4v av[4];
#pragma unroll
    for (int dg = 0; dg < 4; ++dg)
      av[dg] = *(const short4v*)&Vb[voff[dg]];
    __builtin_amdgcn_s_setprio(1);
#pragma unroll
    for (int dg = 0; dg < 4; ++dg)
#pragma unroll
      for (int g = 0; g < 2; ++g)
        oT[dg][g] = __builtin_amdgcn_mfma_f32_16x16x16bf16_1k(av[dg], pb[g], oT[dg][g], 0, 0, 0);
#pragma unroll
    for (int g = 0; g < 2; ++g)
      oT1[g] = __builtin_amdgcn_mfma_f32_16x16x16bf16_1k(ONES, pb[g], oT1[g], 0, 0, 0);
    __builtin_amdgcn_s_setprio(0);

    __builtin_amdgcn_sched_barrier(0);
    __builtin_amdgcn_s_barrier();          // A: all reads of buf done
    __builtin_amdgcn_sched_barrier(0);
    if (t < 30) {  // prefetch tile t+2 into the buffer just freed
      size_t kt2 = (size_t)(t + 2) * 64;
      u16* Kd = Ksp + buf * 4096;
      u16* Vd = Vsp + buf * 4096;
      gl_lds16(kbase + (kt2 + r0 + srow) * 2304 + sux * 8, Kd + r0 * 64);
      gl_lds16(vbase + (size_t)(r0 + srow) * SEQ + kt2 + sux * 8, Vd + r0 * 64);
      asm volatile("s_waitcnt vmcnt(2)" ::: "memory");  // retire t+1's 2 loads
    } else {
      asm volatile("s_waitcnt vmcnt(0)" ::: "memory");
    }
    __builtin_amdgcn_sched_barrier(0);
    __builtin_amdgcn_s_barrier();          // B: t+1 data visible to all waves
    __builtin_amdgcn_sched_barrier(0);
    buf ^= 1;
  }

  // ---- epilogue: reduce js-partial O^T + l across the 4 js waves ----
  // (t=31's barriers guarantee all K/V reads done -> arena reusable)
  float* LDSw = (float*)arena;             // [2 ws][4 js][16 d][LQP] (16.9 KB)
  float* lsd  = (float*)(arena + 17408);   // [2 ws][4 js][32 q] (1 KB)
  if (lane < 16) {
#pragma unroll
    for (int g = 0; g < 2; ++g)
      lsd[(ws * 4 + js) * 32 + g * 16 + lane] = oT1[g][0];
  }
  // thread map for read phase: qq = tid&63 (q in block), dd2 = tid>>6 (d pair)
  int qq = tid & 63, dd2 = tid >> 6;
  int ws2 = qq >> 5, qx = qq & 31;
  float linv = 0.f;
#pragma unroll
  for (int dg = 0; dg < 4; ++dg) {
    // write phase: wave (ws,js) writes its oT tiles for d-chunk dg
#pragma unroll
    for (int g = 0; g < 2; ++g)
#pragma unroll
      for (int r = 0; r < 4; ++r)
        LDSw[((ws * 4 + js) * 16 + quad * 4 + r) * LQP + g * 16 + l15] = oT[dg][g][r];
    __syncthreads();
    if (dg == 0) {
      float L = lsd[(ws2 * 4 + 0) * 32 + qx] + lsd[(ws2 * 4 + 1) * 32 + qx] +
                lsd[(ws2 * 4 + 2) * 32 + qx] + lsd[(ws2 * 4 + 3) * 32 + qx];
      linv = 1.0f / L;
    }
    // sum phase: thread (qq, dd2) -> q = qq, d = dg*16 + dd2*2 + {0,1}
    float sv[2];
#pragma unroll
    for (int hlf = 0; hlf < 2; ++hlf) {
      int dloc = dd2 * 2 + hlf;
      float a = LDSw[((ws2 * 4 + 0) * 16 + dloc) * LQP + qx] +
                LDSw[((ws2 * 4 + 1) * 16 + dloc) * LQP + qx] +
                LDSw[((ws2 * 4 + 2) * 16 + dloc) * LQP + qx] +
                LDSw[((ws2 * 4 + 3) * 16 + dloc) * LQP + qx];
      sv[hlf] = a * linv;
    }
    size_t addr = (base + qt + qq) * DIM + h * HD + dg * 16 + dd2 * 2;
    *(unsigned*)&out[addr] = pku32(sv[0], sv[1]);
    __syncthreads();  // before next chunk reuses LDSw
  }
}

extern "C" void kernel_launch(void* const* d_in, const int* in_sizes, int n_in,
                              void* d_out, int out_size, void* d_ws, size_t ws_size,
                              hipStream_t stream) {
  const float* x     = (const float*)d_in[0];
  const float* ln1w  = (const float*)d_in[1];
  const float* ln1b  = (const float*)d_in[2];
  const float* qkvw  = (const float*)d_in[3];
  const float* qkvbi = (const float*)d_in[4];
  const float* projw = (const float*)d_in[5];
  const float* projb = (const float*)d_in[6];
  const float* ln2w  = (const float*)d_in[7];
  const float* ln2b  = (const float*)d_in[8];
  const float* l1w   = (const float*)d_in[9];
  const float* l1b   = (const float*)d_in[10];
  const float* l2w   = (const float*)d_in[11];
  const float* l2b   = (const float*)d_in[12];
  float* out = (float*)d_out;

  char* w = (char*)d_ws;
  u16*   h     = (u16*)w;   w += (size_t)NTOK * DIM * 2;          // 6.3 MB
  u16*   qkvB  = (u16*)w;                                         // 18.9 MB (union)
  u16*   mid   = (u16*)w;   w += (size_t)NTOK * 3072 * 2;         // 25.2 MB union
  u16*   attnb = (u16*)w;   w += (size_t)NTOK * DIM * 2;          // 6.3 MB
  float* x2    = (float*)w; w += (size_t)NTOK * DIM * 4;          // 12.6 MB
  u16*   vTb   = (u16*)w;   w += (size_t)NTOK * DIM * 2;          // 6.3 MB
  u16*   qkvwt = (u16*)w;   w += (size_t)DIM * 2304 * 2;
  u16*   projwt= (u16*)w;   w += (size_t)DIM * DIM * 2;
  u16*   l1wt  = (u16*)w;   w += (size_t)DIM * 3072 * 2;
  u16*   l2wt  = (u16*)w;   w += (size_t)3072 * DIM * 2;
  float* Pbuf  = (float*)w; w += (size_t)NTOK * DIM * 4;          // 12.6 MB (split-K P1)

  wcvt_all<<<6912, 256, 0, stream>>>(qkvw, projw, l1w, l2w,
                                     qkvwt, projwt, l1wt, l2wt);

  ln_kernel<<<NTOK, 256, 0, stream>>>(x, ln1w, ln1b, h);
  bgemm_kernel<<<dim3(2304 / 128, NTOK / 128), 256, 0, stream>>>(
      h, qkvwt, qkvbi, qkvB, NTOK, 2304, DIM, 0, 1);
  vtr_kernel<<<dim3(768 / 32, SEQ / 32, 2), 256, 0, stream>>>(qkvB, vTb);
  attn_kernel<<<dim3(SEQ / 64, HEADS, 2), 512, 0, stream>>>(qkvB, vTb, attnb);

  // proj: split-K x2 -> x2 + Pbuf; fused reduce(+bias+x residual) + LN2
  bgemm_splitk<<<dim3(DIM / 64, NTOK / 128, 2), 256, 0, stream>>>(
      attnb, projwt, x2, Pbuf, NTOK, DIM, DIM);
  redln_kernel<<<NTOK, 256, 0, stream>>>(x2, Pbuf, projb, x, x2, ln2w, ln2b, h);

  bgemm_kernel<<<dim3(3072 / 128, NTOK / 128), 256, 0, stream>>>(
      h, l1wt, l1b, mid, NTOK, 3072, DIM, 1, 0);

  // lin2: split-K x2 -> out + Pbuf; reduce adds bias + x2 residual
  bgemm_splitk<<<dim3(DIM / 64, NTOK / 128, 2), 256, 0, stream>>>(
      mid, l2wt, out, Pbuf, NTOK, DIM, 3072);
  red_kernel<<<NTOK * DIM / 1024, 256, 0, stream>>>(out, Pbuf, l2b, x2, out, DIM);
}